// Round 5
// baseline (396.845 us; speedup 1.0000x reference)
//
#include <hip/hip_runtime.h>

// B=2, N=2048, E=2048, H=16, D=128.
// Pipeline: cast fp32->bf16 (1 launch), qkv = x@[Wq;Wkv]^T (fused GEMM, bf16),
// V-transpose -> Vt[b][f][n], flash attention S^T formulation (32x32x16 MFMA,
// 128-row Q tiles, 4 waves, DOUBLE-BUFFERED K/V LDS staging via global_load_lds,
// register-only P exchange, XCD-swizzled block ids), out = y@Wout^T (fp32).

typedef __bf16 bf16;
typedef bf16 bf16x2 __attribute__((ext_vector_type(2)));
typedef bf16 bf16x4 __attribute__((ext_vector_type(4)));
typedef bf16 bf16x8 __attribute__((ext_vector_type(8)));
typedef float f32x4 __attribute__((ext_vector_type(4)));
typedef float f32x16 __attribute__((ext_vector_type(16)));

typedef const __attribute__((address_space(1))) void cg_void;
typedef __attribute__((address_space(3))) void lds_void;

#define MFMA16(a, b, c) __builtin_amdgcn_mfma_f32_16x16x32_bf16((a), (b), (c), 0, 0, 0)
#define MFMA32(a, b, c) __builtin_amdgcn_mfma_f32_32x32x16_bf16((a), (b), (c), 0, 0, 0)

__device__ __forceinline__ void async_load16(const bf16* g, bf16* l) {
  __builtin_amdgcn_global_load_lds((cg_void*)g, (lds_void*)l, 16, 0, 0);
}

// ---------------- merged cast fp32 -> bf16 ----------------
__global__ __launch_bounds__(256) void cast_all_kernel(
    const float* __restrict__ x, const float* __restrict__ wq,
    const float* __restrict__ wkv, const float* __restrict__ wout,
    bf16* __restrict__ xb, bf16* __restrict__ wqkvb, bf16* __restrict__ woutb) {
  long i = (long)blockIdx.x * 256 + threadIdx.x;  // 8-elem chunks
  const float* src; bf16* dst; long off;
  if (i < 1048576)      { src = x;    dst = xb;            off = i; }
  else if (i < 2621440) { src = wq;   dst = wqkvb;         off = i - 1048576;
                          if (off >= 524288) { src = wkv; dst = wqkvb + 4194304; off -= 524288; } }
  else                  { src = wout; dst = woutb;         off = i - 2621440; }
  float4 f0 = ((const float4*)src)[2 * off];
  float4 f1 = ((const float4*)src)[2 * off + 1];
  bf16x8 o;
  o[0] = (bf16)f0.x; o[1] = (bf16)f0.y; o[2] = (bf16)f0.z; o[3] = (bf16)f0.w;
  o[4] = (bf16)f1.x; o[5] = (bf16)f1.y; o[6] = (bf16)f1.z; o[7] = (bf16)f1.w;
  ((bf16x8*)dst)[off] = o;
}

// ---------------- C[M,N] = A[M,K] * B[N,K]^T  (m97 structure) ----------------
template <typename OutT>
__global__ __launch_bounds__(256, 4)
void gemm_bt_kernel(const bf16* __restrict__ A, const bf16* __restrict__ B,
                    OutT* __restrict__ C, int K, int NN) {
  __shared__ __attribute__((aligned(16))) bf16 As[128 * 32];
  __shared__ __attribute__((aligned(16))) bf16 Bs[128 * 32];
  const int tid = threadIdx.x;
  const int wave = tid >> 6, lane = tid & 63;
  const int quad = lane >> 4, l15 = lane & 15;
  const int m0 = blockIdx.y * 128, n0 = blockIdx.x * 128;
  const int wm = (wave >> 1) * 64, wn = (wave & 1) * 64;

  f32x4 acc[4][4];
#pragma unroll
  for (int i = 0; i < 4; ++i)
#pragma unroll
    for (int j = 0; j < 4; ++j) acc[i][j] = {0.f, 0.f, 0.f, 0.f};

  const int srow = tid >> 2;
  const int scol = (tid & 3) * 8;
  const bf16* aG = A + (size_t)(m0 + srow) * K + scol;
  const bf16* bG = B + (size_t)(n0 + srow) * K + scol;
  bf16* aL = As + srow * 32 + scol;
  bf16* bL = Bs + srow * 32 + scol;
  const size_t gstep = (size_t)64 * K;

  for (int kt = 0; kt < K; kt += 32) {
    __syncthreads();
    async_load16(aG, aL);
    async_load16(aG + gstep, aL + 64 * 32);
    async_load16(bG, bL);
    async_load16(bG + gstep, bL + 64 * 32);
    aG += 32; bG += 32;
    __syncthreads();

    bf16x8 af[4], bfr[4];
#pragma unroll
    for (int i = 0; i < 4; ++i)
      af[i] = *(const bf16x8*)(As + (wm + i * 16 + l15) * 32 + quad * 8);
#pragma unroll
    for (int j = 0; j < 4; ++j)
      bfr[j] = *(const bf16x8*)(Bs + (wn + j * 16 + l15) * 32 + quad * 8);
#pragma unroll
    for (int i = 0; i < 4; ++i)
#pragma unroll
      for (int j = 0; j < 4; ++j) acc[i][j] = MFMA16(af[i], bfr[j], acc[i][j]);
  }

#pragma unroll
  for (int i = 0; i < 4; ++i) {
#pragma unroll
    for (int r = 0; r < 4; ++r) {
      int row = m0 + wm + i * 16 + quad * 4 + r;
      size_t base = (size_t)row * NN + n0 + wn + l15;
#pragma unroll
      for (int j = 0; j < 4; ++j) C[base + j * 16] = (OutT)acc[i][j][r];
    }
  }
}

// ---------------- V transpose: qkv V-cols [b,n,4096+f] -> Vt [b,f,n] ----------
__global__ __launch_bounds__(256) void vtrans_kernel(const bf16* __restrict__ qkvb,
                                                     bf16* __restrict__ vt) {
  constexpr int QKV = 6144, NSEQ = 2048, E = 2048;
  __shared__ __attribute__((aligned(16))) bf16 Ts[64 * 64];
  const int t = threadIdx.x;
  const int n0 = blockIdx.x * 64, f0 = blockIdx.y * 64, bb = blockIdx.z;
#pragma unroll
  for (int p = 0; p < 2; ++p) {
    int c = p * 256 + t;
    int i = c >> 3, jc = c & 7;
    bf16x8 v = *(const bf16x8*)(qkvb + (size_t)(bb * NSEQ + n0 + i) * QKV + 4096 + f0 + jc * 8);
    *(bf16x8*)(Ts + i * 64 + ((jc + i) & 7) * 8) = v;  // rotate chunk by row
  }
  __syncthreads();
#pragma unroll
  for (int p = 0; p < 2; ++p) {
    int c = p * 256 + t;
    int fl = c >> 3, nl = (c & 7) * 8;
    bf16x8 o;
#pragma unroll
    for (int k = 0; k < 8; ++k) {
      int row = nl + k;
      o[k] = Ts[row * 64 + (((fl >> 3) + row) & 7) * 8 + (fl & 7)];
    }
    *(bf16x8*)(vt + (size_t)(bb * E + f0 + fl) * NSEQ + n0 + nl) = o;
  }
}

// ---------------- flash attention, causal, S^T, double-buffered ---------------
// grid = 512 blocks 1-D; id&7 selects XCD (round-robin dispatch) so all 16 slots
// of one bh share an XCD's L2. 256 threads (4 waves), Q-tile = 128 rows.
// K/V tiles (64 tokens) double-buffered in 64 KB LDS: per iter, ONE barrier
// drains the prefetch issued a full compute-phase earlier, then next prefetch
// is issued before compute -> load latency hidden behind MFMA+softmax.
__global__ __launch_bounds__(256, 2)
void attn_kernel(const bf16* __restrict__ qkv, const bf16* __restrict__ vt,
                 bf16* __restrict__ yb) {
  constexpr int NSEQ = 2048, E = 2048, QKV = 6144;
  __shared__ __attribute__((aligned(16))) bf16 Ks[2][64 * 128];   // [tok][d], XOR-swizzled
  __shared__ __attribute__((aligned(16))) bf16 Vs[2][128 * 64];   // [d][tok], XOR-swizzled
  const int tid = threadIdx.x;
  const int wave = tid >> 6, lane = tid & 63;
  const int l31 = lane & 31, half = lane >> 5;
  const int id = blockIdx.x;
  const int slot = (id >> 3) & 15;
  const int bh = (id & 7) | ((id >> 7) << 3);   // 16 consecutive-mod-8 ids = same bh
  const int b = bh >> 4, h = bh & 15;
  const int qt = (slot < 8) ? slot : 23 - slot; // resident pairs sum to 34 iters
  const float c1 = 0.08838834764831845f * 1.44269504088896f;  // scale * log2(e)

  // staging geometry (256 threads)
  const int krow_s = tid >> 4, kch_s = tid & 15;  // K: 16 chunks/row
  const int vrow_s = tid >> 3, vch_s = tid & 7;   // V: 8 chunks/row
  const bf16* kg = qkv + (size_t)(b * NSEQ) * QKV + 2048 + h * 128;
  const bf16* vg = vt + (size_t)b * E * NSEQ + (size_t)(h * 128) * NSEQ;

  const int diag = 2 * qt + (wave >> 1);  // this wave's diagonal 64-token tile
  const int ktmax = 2 * qt + 1;

  // ---- prefetch tile 0 into buffer 0 ----
  {
    bf16* kdst = Ks[0] + tid * 8;
    bf16* vdst = Vs[0] + tid * 8;
#pragma unroll
    for (int p = 0; p < 4; ++p) {
      int r = p * 16 + krow_s;
      async_load16(kg + (size_t)r * QKV + (kch_s ^ (r & 7)) * 8, kdst + p * 2048);
    }
#pragma unroll
    for (int p = 0; p < 4; ++p) {
      int r = p * 32 + vrow_s;
      async_load16(vg + (size_t)r * NSEQ + (vch_s ^ (r & 7)) * 8, vdst + p * 2048);
    }
  }

  const int qrow = qt * 128 + wave * 32 + l31;  // this lane's q column (global)
  bf16x8 qf[8];
  {
    const bf16* qp = qkv + (size_t)(b * NSEQ + qrow) * QKV + h * 128 + half * 8;
#pragma unroll
    for (int k8 = 0; k8 < 8; ++k8) qf[k8] = *(const bf16x8*)(qp + k8 * 16);
  }

  float m = -3.0e38f, l = 0.f;
  f32x16 accO[4];
#pragma unroll
  for (int md = 0; md < 4; ++md)
#pragma unroll
    for (int r = 0; r < 16; ++r) accO[md][r] = 0.f;

  union PU { unsigned u; bf16x2 h; };
  union FU { bf16x8 v; unsigned u[4]; };

  for (int kt = 0; kt <= ktmax; ++kt) {
    const int cur = kt & 1;
    __syncthreads();  // vmcnt(0) drain: buffer `cur` (prefetched last iter) ready

    if (kt < ktmax) {  // prefetch next tile into the other buffer
      const int nxt = kt + 1;
      bf16* kdst = Ks[1 - cur] + tid * 8;
      bf16* vdst = Vs[1 - cur] + tid * 8;
#pragma unroll
      for (int p = 0; p < 4; ++p) {
        int r = p * 16 + krow_s;
        async_load16(kg + (size_t)(nxt * 64 + r) * QKV + (kch_s ^ (r & 7)) * 8, kdst + p * 2048);
      }
#pragma unroll
      for (int p = 0; p < 4; ++p) {
        int r = p * 32 + vrow_s;
        async_load16(vg + (size_t)r * NSEQ + nxt * 64 + (vch_s ^ (r & 7)) * 8, vdst + p * 2048);
      }
    }

    if (kt > diag) continue;  // fully-masked tile for this wave

    const bf16* ks = Ks[cur];
    const bf16* vs = Vs[cur];

    // ---- S^T = K * Q^T : two 32x32 tiles (tok x q) ----
    f32x16 st[2];
#pragma unroll
    for (int mt = 0; mt < 2; ++mt)
#pragma unroll
      for (int r = 0; r < 16; ++r) st[mt][r] = 0.f;
#pragma unroll
    for (int k8 = 0; k8 < 8; ++k8) {
#pragma unroll
      for (int mt = 0; mt < 2; ++mt) {
        int row = mt * 32 + l31;
        int sl = (k8 * 2 + half) ^ (row & 7);
        bf16x8 kf = *(const bf16x8*)(ks + row * 128 + sl * 8);
        st[mt] = MFMA32(kf, qf[k8], st[mt]);
      }
    }

    // causal mask (diagonal tile only); C row = (r&3)+8*(r>>2)+4*half
    if (kt == diag) {
#pragma unroll
      for (int mt = 0; mt < 2; ++mt)
#pragma unroll
        for (int r = 0; r < 16; ++r) {
          int t = kt * 64 + mt * 32 + (r & 3) + 8 * (r >> 2) + 4 * half;
          if (t > qrow) st[mt][r] = -3.0e38f;
        }
    }

    // ---- online softmax: in-lane + one cross-half shuffle ----
    float mx = -3.0e38f;
#pragma unroll
    for (int mt = 0; mt < 2; ++mt)
#pragma unroll
      for (int r = 0; r < 16; ++r) mx = fmaxf(mx, st[mt][r]);
    mx = fmaxf(mx, __shfl_xor(mx, 32));
    float mnew = fmaxf(m, mx);
    float alpha = exp2f((m - mnew) * c1);
    float mc = mnew * c1;
    m = mnew;

    float psum = 0.f;
    unsigned pown[2][4][2];  // packed bf16 pairs: [mt][quad qd=r>>2][pair]
#pragma unroll
    for (int mt = 0; mt < 2; ++mt)
#pragma unroll
      for (int qd = 0; qd < 4; ++qd)
#pragma unroll
        for (int pr = 0; pr < 2; ++pr) {
          float p0 = exp2f(st[mt][qd * 4 + pr * 2] * c1 - mc);
          float p1 = exp2f(st[mt][qd * 4 + pr * 2 + 1] * c1 - mc);
          psum += p0 + p1;
          PU a; a.h[0] = (bf16)p0; a.h[1] = (bf16)p1;
          pown[mt][qd][pr] = a.u;
        }
    psum += __shfl_xor(psum, 32);
    l = l * alpha + psum;

#pragma unroll
    for (int md = 0; md < 4; ++md)
#pragma unroll
      for (int r = 0; r < 16; ++r) accO[md][r] *= alpha;

    // ---- O^T += V^T * P^T ; P fragments built by half-wave exchange ----
#pragma unroll
    for (int mt = 0; mt < 2; ++mt)
#pragma unroll
      for (int c = 0; c < 2; ++c) {
        const int qa = 2 * c, qb = 2 * c + 1;
        unsigned ra0 = __shfl_xor(pown[mt][qa][0], 32);
        unsigned ra1 = __shfl_xor(pown[mt][qa][1], 32);
        unsigned rb0 = __shfl_xor(pown[mt][qb][0], 32);
        unsigned rb1 = __shfl_xor(pown[mt][qb][1], 32);
        FU f;
        f.u[0] = half ? rb0 : pown[mt][qa][0];
        f.u[1] = half ? rb1 : pown[mt][qa][1];
        f.u[2] = half ? pown[mt][qb][0] : ra0;
        f.u[3] = half ? pown[mt][qb][1] : ra1;
        const int kk = mt * 2 + c;
#pragma unroll
        for (int md = 0; md < 4; ++md) {
          int row = md * 32 + l31;
          bf16x8 vf = *(const bf16x8*)(vs + row * 64 + (((kk * 2 + half) ^ (row & 7)) * 8));
          accO[md] = MFMA32(vf, f.v, accO[md]);
        }
      }
  }

  // ---- normalize, write y[b, q, h*128 + d] ----
  float invl = 1.0f / l;
  bf16* yp = yb + (size_t)(b * NSEQ + qrow) * E + h * 128;
#pragma unroll
  for (int md = 0; md < 4; ++md)
#pragma unroll
    for (int rq = 0; rq < 4; ++rq) {
      bf16x4 o;
#pragma unroll
      for (int i = 0; i < 4; ++i) o[i] = (bf16)(accO[md][rq * 4 + i] * invl);
      *(bf16x4*)(yp + md * 32 + rq * 8 + half * 4) = o;
    }
}

// ---------------- launch ----------------
extern "C" void kernel_launch(void* const* d_in, const int* in_sizes, int n_in,
                              void* d_out, int out_size, void* d_ws, size_t ws_size,
                              hipStream_t stream) {
  const float* x    = (const float*)d_in[0];
  const float* Wq   = (const float*)d_in[1];
  const float* Wkv  = (const float*)d_in[2];
  const float* Wout = (const float*)d_in[3];
  float* out = (float*)d_out;

  constexpr size_t NX = (size_t)2 * 2048 * 2048;  // 8388608
  constexpr size_t NW = (size_t)2048 * 2048;      // 4194304

  bf16* xb     = (bf16*)d_ws;
  bf16* wqkvb  = xb + NX;          // [6144 x 2048] = Wq rows then Wkv rows
  bf16* woutb  = wqkvb + 3 * NW;
  bf16* qkv_b  = woutb + NW;       // [4096 x 6144]: q | k | v per row
  bf16* y_b    = qkv_b + 3 * NX;
  bf16* vt_b   = xb;               // alias: xb dead after qkv GEMM

  cast_all_kernel<<<12288, 256, 0, stream>>>(x, Wq, Wkv, Wout, xb, wqkvb, woutb);

  // qkv = x @ [Wq; Wkv]^T : [4096, 6144]
  gemm_bt_kernel<bf16><<<dim3(48, 32), 256, 0, stream>>>(xb, wqkvb, qkv_b, 2048, 6144);
  // V cols of qkv -> Vt [b, f, n] (overwrites xb)
  vtrans_kernel<<<dim3(32, 32, 2), 256, 0, stream>>>(qkv_b, vt_b);
  // attention -> y [4096, 2048] bf16
  attn_kernel<<<512, 256, 0, stream>>>(qkv_b, vt_b, y_b);
  // out = y @ Wout^T : fp32
  gemm_bt_kernel<float><<<dim3(16, 32), 256, 0, stream>>>(y_b, woutb, out, 2048, 2048);
}

// Round 6
// 383.251 us; speedup vs baseline: 1.0355x; 1.0355x over previous
//
#include <hip/hip_runtime.h>

// B=2, N=2048, E=2048, H=16, D=128.
// Pipeline: cast fp32->bf16 (1 launch), fused GEMM qkv = x@[Wq;Wkv]^T which
// stores q|k (stride 4096) and V TRANSPOSED (vt[b][f][n]) from its epilogue,
// flash attention S^T formulation (32x32x16 MFMA, 128-row Q tiles, 4 waves,
// double-buffered K/V LDS staging, register-only P exchange, XCD-paired
// complementary qt balance), out = y@Wout^T (fp32).

typedef __bf16 bf16;
typedef bf16 bf16x2 __attribute__((ext_vector_type(2)));
typedef bf16 bf16x4 __attribute__((ext_vector_type(4)));
typedef bf16 bf16x8 __attribute__((ext_vector_type(8)));
typedef float f32x4 __attribute__((ext_vector_type(4)));
typedef float f32x16 __attribute__((ext_vector_type(16)));

typedef const __attribute__((address_space(1))) void cg_void;
typedef __attribute__((address_space(3))) void lds_void;

#define MFMA16(a, b, c) __builtin_amdgcn_mfma_f32_16x16x32_bf16((a), (b), (c), 0, 0, 0)
#define MFMA32(a, b, c) __builtin_amdgcn_mfma_f32_32x32x16_bf16((a), (b), (c), 0, 0, 0)

__device__ __forceinline__ void async_load16(const bf16* g, bf16* l) {
  __builtin_amdgcn_global_load_lds((cg_void*)g, (lds_void*)l, 16, 0, 0);
}

// ---------------- merged cast fp32 -> bf16 ----------------
__global__ __launch_bounds__(256) void cast_all_kernel(
    const float* __restrict__ x, const float* __restrict__ wq,
    const float* __restrict__ wkv, const float* __restrict__ wout,
    bf16* __restrict__ xb, bf16* __restrict__ wqkvb, bf16* __restrict__ woutb) {
  long i = (long)blockIdx.x * 256 + threadIdx.x;  // 8-elem chunks
  const float* src; bf16* dst; long off;
  if (i < 1048576)      { src = x;    dst = xb;            off = i; }
  else if (i < 2621440) { src = wq;   dst = wqkvb;         off = i - 1048576;
                          if (off >= 524288) { src = wkv; dst = wqkvb + 4194304; off -= 524288; } }
  else                  { src = wout; dst = woutb;         off = i - 2621440; }
  float4 f0 = ((const float4*)src)[2 * off];
  float4 f1 = ((const float4*)src)[2 * off + 1];
  bf16x8 o;
  o[0] = (bf16)f0.x; o[1] = (bf16)f0.y; o[2] = (bf16)f0.z; o[3] = (bf16)f0.w;
  o[4] = (bf16)f1.x; o[5] = (bf16)f1.y; o[6] = (bf16)f1.z; o[7] = (bf16)f1.w;
  ((bf16x8*)dst)[off] = o;
}

// ---------------- C[M,N] = A[M,K] * B[N,K]^T  (m97 structure) ----------------
// SPLITV: blocks with n0>=4096 are V columns -> write TRANSPOSED to vt[b][f][n]
// (f = col-4096, n = row & 2047, b = row >> 11) via LDS-staged 64-row passes.
// q/k blocks store to C with stride NN (=4096). Non-SPLITV: plain store.
template <typename OutT, bool SPLITV>
__global__ __launch_bounds__(256, 4)
void gemm_bt_kernel(const bf16* __restrict__ A, const bf16* __restrict__ B,
                    OutT* __restrict__ C, int K, int NN, bf16* __restrict__ vt) {
  __shared__ __attribute__((aligned(16))) bf16 smem[8192];  // As|Bs, reused for transpose
  bf16* As = smem;
  bf16* Bs = smem + 4096;
  const int tid = threadIdx.x;
  const int wave = tid >> 6, lane = tid & 63;
  const int quad = lane >> 4, l15 = lane & 15;
  const int m0 = blockIdx.y * 128, n0 = blockIdx.x * 128;
  const int wm = (wave >> 1) * 64, wn = (wave & 1) * 64;

  f32x4 acc[4][4];
#pragma unroll
  for (int i = 0; i < 4; ++i)
#pragma unroll
    for (int j = 0; j < 4; ++j) acc[i][j] = {0.f, 0.f, 0.f, 0.f};

  const int srow = tid >> 2;
  const int scol = (tid & 3) * 8;
  const bf16* aG = A + (size_t)(m0 + srow) * K + scol;
  const bf16* bG = B + (size_t)(n0 + srow) * K + scol;
  bf16* aL = As + srow * 32 + scol;
  bf16* bL = Bs + srow * 32 + scol;
  const size_t gstep = (size_t)64 * K;

  for (int kt = 0; kt < K; kt += 32) {
    __syncthreads();
    async_load16(aG, aL);
    async_load16(aG + gstep, aL + 64 * 32);
    async_load16(bG, bL);
    async_load16(bG + gstep, bL + 64 * 32);
    aG += 32; bG += 32;
    __syncthreads();

    bf16x8 af[4], bfr[4];
#pragma unroll
    for (int i = 0; i < 4; ++i)
      af[i] = *(const bf16x8*)(As + (wm + i * 16 + l15) * 32 + quad * 8);
#pragma unroll
    for (int j = 0; j < 4; ++j)
      bfr[j] = *(const bf16x8*)(Bs + (wn + j * 16 + l15) * 32 + quad * 8);
#pragma unroll
    for (int i = 0; i < 4; ++i)
#pragma unroll
      for (int j = 0; j < 4; ++j) acc[i][j] = MFMA16(af[i], bfr[j], acc[i][j]);
  }

  if (SPLITV && n0 >= 4096) {
    // ---- transposed V write: vt[b][f][n] ----
    const int f0 = n0 - 4096;
    const int b = m0 >> 11;
    const int nbase = m0 & 2047;
#pragma unroll
    for (int p = 0; p < 2; ++p) {  // row-half [p*64, p*64+64)
      __syncthreads();
      if ((wave >> 1) == p) {
#pragma unroll
        for (int i = 0; i < 4; ++i)
#pragma unroll
          for (int r = 0; r < 4; ++r) {
            int nl = i * 16 + quad * 4 + r;  // row within this 64-half
#pragma unroll
            for (int j = 0; j < 4; ++j) {
              int f = wn + j * 16 + l15;
              smem[nl * 128 + ((((f >> 3) + nl) & 15) * 8) + (f & 7)] = (bf16)acc[i][j][r];
            }
          }
      }
      __syncthreads();
#pragma unroll
      for (int c = 0; c < 4; ++c) {
        int idx = c * 256 + tid;
        int f = idx >> 3, n8 = idx & 7;
        bf16x8 o;
#pragma unroll
        for (int k = 0; k < 8; ++k) {
          int nl = n8 * 8 + k;
          o[k] = smem[nl * 128 + ((((f >> 3) + nl) & 15) * 8) + (f & 7)];
        }
        *(bf16x8*)(vt + ((size_t)(b * 2048 + f0 + f)) * 2048 + nbase + p * 64 + n8 * 8) = o;
      }
    }
    return;
  }

#pragma unroll
  for (int i = 0; i < 4; ++i) {
#pragma unroll
    for (int r = 0; r < 4; ++r) {
      int row = m0 + wm + i * 16 + quad * 4 + r;
      size_t base = (size_t)row * NN + n0 + wn + l15;
#pragma unroll
      for (int j = 0; j < 4; ++j) C[base + j * 16] = (OutT)acc[i][j][r];
    }
  }
}

// ---------------- flash attention, causal, S^T, double-buffered ---------------
// grid = 512 blocks 1-D. Decode: xcd = id&7; bh = (id&7)|(((id>>3)&3)<<3);
// slot = (id>>5)&15; qt = slot<8 ? slot : 23-slot. Resident pair (id, id+256)
// shares bh/XCD and has complementary qt (sum 15) -> every CU 34 tile-iters.
// 256 threads (4 waves), Q-tile = 128 rows. K/V (64-token tiles) double-buffered
// in 64 KB LDS: one barrier/iter drains the prefetch issued a full compute
// phase earlier; next prefetch issued before compute -> latency hidden.
__global__ __launch_bounds__(256, 2)
void attn_kernel(const bf16* __restrict__ qk, const bf16* __restrict__ vt,
                 bf16* __restrict__ yb) {
  constexpr int NSEQ = 2048, E = 2048, QKS = 4096;
  __shared__ __attribute__((aligned(16))) bf16 Ks[2][64 * 128];   // [tok][d], XOR-swizzled
  __shared__ __attribute__((aligned(16))) bf16 Vs[2][128 * 64];   // [d][tok], XOR-swizzled
  const int tid = threadIdx.x;
  const int wave = tid >> 6, lane = tid & 63;
  const int l31 = lane & 31, half = lane >> 5;
  const int id = blockIdx.x;
  const int slot = (id >> 5) & 15;
  const int bh = (id & 7) | (((id >> 3) & 3) << 3);
  const int b = bh >> 4, h = bh & 15;
  const int qt = (slot < 8) ? slot : 23 - slot;
  const float c1 = 0.08838834764831845f * 1.44269504088896f;  // scale * log2(e)

  // staging geometry (256 threads)
  const int krow_s = tid >> 4, kch_s = tid & 15;  // K: 16 chunks/row
  const int vrow_s = tid >> 3, vch_s = tid & 7;   // V: 8 chunks/row
  const bf16* kg = qk + (size_t)(b * NSEQ) * QKS + 2048 + h * 128;
  const bf16* vg = vt + (size_t)b * E * NSEQ + (size_t)(h * 128) * NSEQ;

  const int diag = 2 * qt + (wave >> 1);  // this wave's diagonal 64-token tile
  const int ktmax = 2 * qt + 1;

  // ---- prefetch tile 0 into buffer 0 ----
  {
    bf16* kdst = Ks[0] + tid * 8;
    bf16* vdst = Vs[0] + tid * 8;
#pragma unroll
    for (int p = 0; p < 4; ++p) {
      int r = p * 16 + krow_s;
      async_load16(kg + (size_t)r * QKS + (kch_s ^ (r & 7)) * 8, kdst + p * 2048);
    }
#pragma unroll
    for (int p = 0; p < 4; ++p) {
      int r = p * 32 + vrow_s;
      async_load16(vg + (size_t)r * NSEQ + (vch_s ^ (r & 7)) * 8, vdst + p * 2048);
    }
  }

  const int qrow = qt * 128 + wave * 32 + l31;  // this lane's q column (global)
  bf16x8 qf[8];
  {
    const bf16* qp = qk + (size_t)(b * NSEQ + qrow) * QKS + h * 128 + half * 8;
#pragma unroll
    for (int k8 = 0; k8 < 8; ++k8) qf[k8] = *(const bf16x8*)(qp + k8 * 16);
  }

  float m = -3.0e38f, l = 0.f;
  f32x16 accO[4];
#pragma unroll
  for (int md = 0; md < 4; ++md)
#pragma unroll
    for (int r = 0; r < 16; ++r) accO[md][r] = 0.f;

  union PU { unsigned u; bf16x2 h; };
  union FU { bf16x8 v; unsigned u[4]; };

  for (int kt = 0; kt <= ktmax; ++kt) {
    const int cur = kt & 1;
    __syncthreads();  // vmcnt(0) drain: buffer `cur` (prefetched last iter) ready

    if (kt < ktmax) {  // prefetch next tile into the other buffer
      const int nxt = kt + 1;
      bf16* kdst = Ks[1 - cur] + tid * 8;
      bf16* vdst = Vs[1 - cur] + tid * 8;
#pragma unroll
      for (int p = 0; p < 4; ++p) {
        int r = p * 16 + krow_s;
        async_load16(kg + (size_t)(nxt * 64 + r) * QKS + (kch_s ^ (r & 7)) * 8, kdst + p * 2048);
      }
#pragma unroll
      for (int p = 0; p < 4; ++p) {
        int r = p * 32 + vrow_s;
        async_load16(vg + (size_t)r * NSEQ + nxt * 64 + (vch_s ^ (r & 7)) * 8, vdst + p * 2048);
      }
    }

    if (kt > diag) continue;  // fully-masked tile for this wave

    const bf16* ks = Ks[cur];
    const bf16* vs = Vs[cur];

    // ---- S^T = K * Q^T : two 32x32 tiles (tok x q) ----
    f32x16 st[2];
#pragma unroll
    for (int mt = 0; mt < 2; ++mt)
#pragma unroll
      for (int r = 0; r < 16; ++r) st[mt][r] = 0.f;
#pragma unroll
    for (int k8 = 0; k8 < 8; ++k8) {
#pragma unroll
      for (int mt = 0; mt < 2; ++mt) {
        int row = mt * 32 + l31;
        int sl = (k8 * 2 + half) ^ (row & 7);
        bf16x8 kf = *(const bf16x8*)(ks + row * 128 + sl * 8);
        st[mt] = MFMA32(kf, qf[k8], st[mt]);
      }
    }

    // causal mask (diagonal tile only); C row = (r&3)+8*(r>>2)+4*half
    if (kt == diag) {
#pragma unroll
      for (int mt = 0; mt < 2; ++mt)
#pragma unroll
        for (int r = 0; r < 16; ++r) {
          int t = kt * 64 + mt * 32 + (r & 3) + 8 * (r >> 2) + 4 * half;
          if (t > qrow) st[mt][r] = -3.0e38f;
        }
    }

    // ---- online softmax: in-lane + one cross-half shuffle ----
    float mx = -3.0e38f;
#pragma unroll
    for (int mt = 0; mt < 2; ++mt)
#pragma unroll
      for (int r = 0; r < 16; ++r) mx = fmaxf(mx, st[mt][r]);
    mx = fmaxf(mx, __shfl_xor(mx, 32));
    float mnew = fmaxf(m, mx);
    float alpha = exp2f((m - mnew) * c1);
    float mc = mnew * c1;
    m = mnew;

    float psum = 0.f;
    unsigned pown[2][4][2];  // packed bf16 pairs: [mt][quad qd=r>>2][pair]
#pragma unroll
    for (int mt = 0; mt < 2; ++mt)
#pragma unroll
      for (int qd = 0; qd < 4; ++qd)
#pragma unroll
        for (int pr = 0; pr < 2; ++pr) {
          float p0 = exp2f(st[mt][qd * 4 + pr * 2] * c1 - mc);
          float p1 = exp2f(st[mt][qd * 4 + pr * 2 + 1] * c1 - mc);
          psum += p0 + p1;
          PU a; a.h[0] = (bf16)p0; a.h[1] = (bf16)p1;
          pown[mt][qd][pr] = a.u;
        }
    psum += __shfl_xor(psum, 32);
    l = l * alpha + psum;

#pragma unroll
    for (int md = 0; md < 4; ++md)
#pragma unroll
      for (int r = 0; r < 16; ++r) accO[md][r] *= alpha;

    // ---- O^T += V^T * P^T ; P fragments built by half-wave exchange ----
#pragma unroll
    for (int mt = 0; mt < 2; ++mt)
#pragma unroll
      for (int c = 0; c < 2; ++c) {
        const int qa = 2 * c, qb = 2 * c + 1;
        unsigned ra0 = __shfl_xor(pown[mt][qa][0], 32);
        unsigned ra1 = __shfl_xor(pown[mt][qa][1], 32);
        unsigned rb0 = __shfl_xor(pown[mt][qb][0], 32);
        unsigned rb1 = __shfl_xor(pown[mt][qb][1], 32);
        FU f;
        f.u[0] = half ? rb0 : pown[mt][qa][0];
        f.u[1] = half ? rb1 : pown[mt][qa][1];
        f.u[2] = half ? pown[mt][qb][0] : ra0;
        f.u[3] = half ? pown[mt][qb][1] : ra1;
        const int kk = mt * 2 + c;
#pragma unroll
        for (int md = 0; md < 4; ++md) {
          int row = md * 32 + l31;
          bf16x8 vf = *(const bf16x8*)(vs + row * 64 + (((kk * 2 + half) ^ (row & 7)) * 8));
          accO[md] = MFMA32(vf, f.v, accO[md]);
        }
      }
  }

  // ---- normalize, write y[b, q, h*128 + d] ----
  float invl = 1.0f / l;
  bf16* yp = yb + (size_t)(b * NSEQ + qrow) * E + h * 128;
#pragma unroll
  for (int md = 0; md < 4; ++md)
#pragma unroll
    for (int rq = 0; rq < 4; ++rq) {
      bf16x4 o;
#pragma unroll
      for (int i = 0; i < 4; ++i) o[i] = (bf16)(accO[md][rq * 4 + i] * invl);
      *(bf16x4*)(yp + md * 32 + rq * 8 + half * 4) = o;
    }
}

// ---------------- launch ----------------
extern "C" void kernel_launch(void* const* d_in, const int* in_sizes, int n_in,
                              void* d_out, int out_size, void* d_ws, size_t ws_size,
                              hipStream_t stream) {
  const float* x    = (const float*)d_in[0];
  const float* Wq   = (const float*)d_in[1];
  const float* Wkv  = (const float*)d_in[2];
  const float* Wout = (const float*)d_in[3];
  float* out = (float*)d_out;

  constexpr size_t NX = (size_t)2 * 2048 * 2048;  // 8388608
  constexpr size_t NW = (size_t)2048 * 2048;      // 4194304

  bf16* xb     = (bf16*)d_ws;
  bf16* wqkvb  = xb + NX;          // [6144 x 2048] = Wq rows then Wkv rows
  bf16* woutb  = wqkvb + 3 * NW;
  bf16* qk_b   = woutb + NW;       // [4096 x 4096]: q | k per row
  bf16* y_b    = qk_b + 2 * NX;
  bf16* vt_b   = y_b + NX;         // [b, f, n] = [2][2048][2048]

  cast_all_kernel<<<12288, 256, 0, stream>>>(x, Wq, Wkv, Wout, xb, wqkvb, woutb);

  // qkv = x @ [Wq; Wkv]^T : q|k -> qk_b (stride 4096), V -> vt_b transposed
  gemm_bt_kernel<bf16, true><<<dim3(48, 32), 256, 0, stream>>>(
      xb, wqkvb, qk_b, 2048, 4096, vt_b);
  // attention -> y [4096, 2048] bf16
  attn_kernel<<<512, 256, 0, stream>>>(qk_b, vt_b, y_b);
  // out = y @ Wout^T : fp32
  gemm_bt_kernel<float, false><<<dim3(16, 32), 256, 0, stream>>>(
      y_b, woutb, out, 2048, 2048, nullptr);
}